// Round 14
// baseline (108.684 us; speedup 1.0000x reference)
//
#include <hip/hip_runtime.h>
#include <math.h>

// Problem constants (fixed by the reference)
#define NBATCH 16
#define CCH    128     // channels C
#define HW     2304    // 48*48 tokens per frame
#define DI     64      // inter_channels CI
#define NTILE  36      // HW / 64 (proj/combine token blocks)
#define HTILE  18      // key tiles per key-half (attn)
#define QBLK   18      // HW / 128 (attn q-blocks)
#define LOG2E  1.44269504088896f

typedef unsigned short u16;
typedef unsigned int   u32;
typedef __bf16   bf16x8 __attribute__((ext_vector_type(8)));
typedef _Float16 f16x8  __attribute__((ext_vector_type(8)));
typedef float    f32x4  __attribute__((ext_vector_type(4)));

__device__ __forceinline__ u16 f2bf_rne(float x) {
    union { float f; u32 u; } v; v.f = x;
    u32 r = (v.u + 0x7FFFu + ((v.u >> 16) & 1u)) >> 16;
    return (u16)r;
}
__device__ __forceinline__ u16 f2h(float x) {
    union { _Float16 h; u16 u; } c; c.h = (_Float16)x; return c.u;
}
__device__ __forceinline__ float exp2v(float x) {   // bare v_exp_f32: D = 2^S0
    float r;
    asm("v_exp_f32 %0, %1" : "=v"(r) : "v"(x));
    return r;
}

// ---------------------------------------------------------------------------
// Kernel 0: one-time W -> fp16 conversion in MFMA B-frag order (validated R10).
// ---------------------------------------------------------------------------
__global__ __launch_bounds__(256) void wprep_kernel(
    const float* __restrict__ Wq, const float* __restrict__ Wk,
    const float* __restrict__ Wv, const float* __restrict__ Wz,
    u16* __restrict__ Wf, u16* __restrict__ Wzf)
{
    const int idx  = blockIdx.x * 256 + threadIdx.x;   // 0..4095
    if (idx < 3072) {
        const int lane = idx & 63;
        const int fi   = idx >> 6;
        const int g = fi >> 2, ks = fi & 3;
        const int lo = lane & 15, hi = lane >> 4;
        const int row = g * 16 + lo;
        const float* src = (row < 64)  ? &Wq[row * CCH]
                         : (row < 128) ? &Wk[(row - 64) * CCH]
                                       : &Wv[(row - 128) * CCH];
        const int c0 = (ks * 4 + hi) * 8;
        float4 a = *(const float4*)&src[c0];
        float4 b = *(const float4*)&src[c0 + 4];
        union { u16 s8[8]; uint4 v; } pk;
        pk.s8[0] = f2h(a.x); pk.s8[1] = f2h(a.y); pk.s8[2] = f2h(a.z); pk.s8[3] = f2h(a.w);
        pk.s8[4] = f2h(b.x); pk.s8[5] = f2h(b.y); pk.s8[6] = f2h(b.z); pk.s8[7] = f2h(b.w);
        *(uint4*)&Wf[(size_t)idx * 8] = pk.v;
    } else {
        const int t    = idx - 3072;
        const int lane = t & 63;
        const int fi   = t >> 6;
        const int g = fi >> 1, ks = fi & 1;
        const int lo = lane & 15, hi = lane >> 4;
        const int row = g * 16 + lo;
        const int d0  = ks * 32 + hi * 8;
        float4 a = *(const float4*)&Wz[row * DI + d0];
        float4 b = *(const float4*)&Wz[row * DI + d0 + 4];
        union { u16 s8[8]; uint4 v; } pk;
        pk.s8[0] = f2h(a.x); pk.s8[1] = f2h(a.y); pk.s8[2] = f2h(a.z); pk.s8[3] = f2h(a.w);
        pk.s8[4] = f2h(b.x); pk.s8[5] = f2h(b.y); pk.s8[6] = f2h(b.z); pk.s8[7] = f2h(b.w);
        *(uint4*)&Wzf[(size_t)t * 8] = pk.v;
    }
}

// ---------------------------------------------------------------------------
// Kernel 1: q/k/v projection fp16 MFMA GEMM (validated R7/R9/R10).
// This round: q pre-scaled by log2(e) so attn's softmax uses bare v_exp_f32
// (2^x) with no per-element multiply.
// ---------------------------------------------------------------------------
__global__ __launch_bounds__(256) void proj_kernel(
    const float* __restrict__ F, const u16* __restrict__ Wf,
    const float* __restrict__ bq, const float* __restrict__ bk,
    const float* __restrict__ bv,
    u16* __restrict__ qo, u16* __restrict__ ko, u16* __restrict__ vto)
{
    __shared__ __align__(16) u16 Fl[64 * 128];
    __shared__ __align__(16) u16 Vt[64 * 72];

    const int tid  = threadIdx.x;
    const int n    = blockIdx.x / NTILE;
    const int p0   = (blockIdx.x % NTILE) * 64;
    const int lane = tid & 63, wave = tid >> 6;
    const int lo   = lane & 15, hi = lane >> 4;

    const float* Fn = F + (size_t)n * CCH * HW;
    #pragma unroll
    for (int i = 0; i < 4; ++i) {
        int s  = tid + i * 256;
        int c0 = (s >> 4) * 2;
        int t0 = (s & 15) * 4;
        const float* fp_ = &Fn[(size_t)c0 * HW + p0 + t0];
        float4 fa = *(const float4*)fp_;
        float4 fb = *(const float4*)(fp_ + HW);
        #pragma unroll
        for (int e = 0; e < 4; ++e) {
            int t = t0 + e;
            u32 w = (u32)f2h((&fa.x)[e]) | ((u32)f2h((&fb.x)[e]) << 16);
            *(u32*)&Fl[t * 128 + (((c0 >> 3) ^ (t & 15)) << 3) + (c0 & 7)] = w;
        }
    }
    __syncthreads();

    const int arow = wave * 16 + lo;
    f16x8 af[4];
    #pragma unroll
    for (int ks = 0; ks < 4; ++ks)
        af[ks] = *(const f16x8*)&Fl[arow * 128 + (((ks * 4 + hi) ^ lo) << 3)];

    f32x4 acc[12];
    #pragma unroll
    for (int g = 0; g < 12; ++g)
        #pragma unroll
        for (int r = 0; r < 4; ++r) acc[g][r] = 0.f;

    #pragma unroll
    for (int g = 0; g < 12; ++g) {
        #pragma unroll
        for (int ks = 0; ks < 4; ++ks) {
            f16x8 bf = *(const f16x8*)&Wf[(size_t)((g * 4 + ks) * 64 + lane) * 8];
            acc[g] = __builtin_amdgcn_mfma_f32_16x16x32_f16(af[ks], bf, acc[g], 0, 0, 0);
        }
    }

    const int twb = p0 + wave * 16 + 4 * hi;
    #pragma unroll
    for (int g = 0; g < 4; ++g) {
        float bQ = bq[g * 16 + lo], bK = bk[g * 16 + lo];
        #pragma unroll
        for (int r = 0; r < 4; ++r) {
            size_t off = ((size_t)n * HW + twb + r) * DI + g * 16 + lo;
            qo[off] = f2h((acc[g][r] + bQ) * LOG2E);   // exp2 pre-scale
            ko[off] = f2h(acc[g + 4][r] + bK);
        }
    }
    #pragma unroll
    for (int g = 0; g < 4; ++g) {
        float bV = bv[g * 16 + lo];
        #pragma unroll
        for (int r = 0; r < 4; ++r)
            Vt[(g * 16 + lo) * 72 + wave * 16 + 4 * hi + r] = f2bf_rne(acc[g + 8][r] + bV);
    }
    __syncthreads();
    #pragma unroll
    for (int i = 0; i < 2; ++i) {
        int s = tid + i * 256;
        int d = s >> 3, c8 = (s & 7) * 8;
        *(uint4*)&vto[((size_t)n * DI + d) * HW + p0 + c8] = *(const uint4*)&Vt[d * 72 + c8];
    }
}

// ---------------------------------------------------------------------------
// Kernel 2: flash attention (R13 structure: pass/key-half/frame/128q blocks,
// grid 1152, 4 waves x Q=32, 32 KB dbuf LDS, partials into d_out regions).
// This round's VALU diet (R13 counters: 46% VALUBusy vs 24% MfmaUtil =
// issue-port bound on softmax VALU):
//  - P = 2^(S') via bare v_exp_f32 (q pre-scaled by log2e in proj)
//  - l computed on the MFMA pipe: l[q] = mfma(pa, ones) row-sums, so the
//    scalar lacc adds AND the epilogue shuffle-reduce disappear (each lane
//    ends with l for exactly its D-layout rows 4hi+r).
// ---------------------------------------------------------------------------
__global__ __launch_bounds__(256, 4) void attn_pass_kernel(
    const u16* __restrict__ q, const u16* __restrict__ k, const u16* __restrict__ vt,
    float* __restrict__ outF, float* __restrict__ lp)
{
    __shared__ __align__(16) u16 smem[16384];     // 32 KiB
    u16* const Kb0 = smem;
    u16* const Kb1 = smem + 4096;
    u16* const Vb0 = smem + 8192;
    u16* const Vb1 = smem + 12288;

    const int tid  = threadIdx.x;
    const int lane = tid & 63;
    const int w4   = tid >> 6;                    // 0..3
    const int lo   = lane & 15, hi = lane >> 4;

    // chunked bijective XCD swizzle: 1152 = 8 * 144
    const int bid  = (int)blockIdx.x;
    const int w    = (bid & 7) * 144 + (bid >> 3);
    const int j    = w / (NBATCH * QBLK);         // pass*2 + half
    const int rem  = w % (NBATCH * QBLK);
    const int n    = rem / QBLK;
    const int qb   = rem % QBLK;
    const int pass = j >> 1, half = j & 1;
    const int P0   = qb * 128;

    const int nb = (pass == 0) ? (n > 0 ? n - 1 : 0)
                               : (n < NBATCH - 1 ? n + 1 : n);
    const u16* kp = k  + (size_t)nb * HW * DI;
    const u16* vp = vt + (size_t)nb * DI * HW;
    const int  kq = half * (HTILE * 64);          // this half's key offset

    // Q fragments (B-operand of swapped QK), two 16-row sets per wave
    f16x8 qfA0, qfA1, qfB0, qfB1;
    {
        const u16* qp = q + ((size_t)n * HW + P0 + w4 * 32 + lo) * DI + hi * 8;
        qfA0 = *(const f16x8*)qp;
        qfA1 = *(const f16x8*)(qp + 32);
        qfB0 = *(const f16x8*)(qp + 16 * DI);
        qfB1 = *(const f16x8*)(qp + 16 * DI + 32);
    }

    // ones B-frag for the l row-sum MFMA (bf16 1.0 = 0x3F80)
    bf16x8 vone;
    #pragma unroll
    for (int e = 0; e < 8; ++e) vone[e] = (__bf16)1.0f;

    // staging geometry: 512 x 16B chunks per 8KB tile; thread covers 2 rows
    const int sch   = tid & 7;
    const int srow0 = tid >> 3;
    const int srow1 = srow0 + 32;
    const int fk0   = (srow0 & 3) | ((srow0 & 8) >> 1);
    const int fk1   = (srow1 & 3) | ((srow1 & 8) >> 1);
    const int koff0 = srow0 * 64 + ((sch ^ fk0) * 8);
    const int koff1 = srow1 * 64 + ((sch ^ fk1) * 8);
    const int voff0 = srow0 * 64 + ((sch ^ (srow0 & 7)) * 8);
    const int voff1 = srow1 * 64 + ((sch ^ (srow1 & 7)) * 8);

    // permuted K A-frag row base: kr_m = krbase + 4*(m&1) + 32*(m>>1)
    const int krbase = 8 * (lo >> 2) + (lo & 3);
    const int xl = lo & 7;

    f32x4 yaccA[4], yaccB[4], laccA4, laccB4;
    #pragma unroll
    for (int nf = 0; nf < 4; ++nf)
        #pragma unroll
        for (int r = 0; r < 4; ++r) { yaccA[nf][r] = 0.f; yaccB[nf][r] = 0.f; }
    #pragma unroll
    for (int r = 0; r < 4; ++r) { laccA4[r] = 0.f; laccB4[r] = 0.f; }

    // prologue: tile0 -> buf0; tile1 -> regs
    uint4 ka0 = *(const uint4*)(kp + (size_t)(kq + srow0) * DI + sch * 8);
    uint4 ka1 = *(const uint4*)(kp + (size_t)(kq + srow1) * DI + sch * 8);
    uint4 va0 = *(const uint4*)(vp + (size_t)srow0 * HW + kq + sch * 8);
    uint4 va1 = *(const uint4*)(vp + (size_t)srow1 * HW + kq + sch * 8);
    *(uint4*)&Kb0[koff0] = ka0;  *(uint4*)&Kb0[koff1] = ka1;
    *(uint4*)&Vb0[voff0] = va0;  *(uint4*)&Vb0[voff1] = va1;
    ka0 = *(const uint4*)(kp + (size_t)(kq + 64 + srow0) * DI + sch * 8);
    ka1 = *(const uint4*)(kp + (size_t)(kq + 64 + srow1) * DI + sch * 8);
    va0 = *(const uint4*)(vp + (size_t)srow0 * HW + kq + 64 + sch * 8);
    va1 = *(const uint4*)(vp + (size_t)srow1 * HW + kq + 64 + sch * 8);
    __syncthreads();

    auto body = [&](int t, const u16* Kc, const u16* Vc, u16* Kn, u16* Vn) {
        // --- swapped QK^T with permuted A rows (both q-sets share K frags) ---
        f32x4 stA[4], stB[4];
        __builtin_amdgcn_s_setprio(1);
        #pragma unroll
        for (int m = 0; m < 4; ++m) {
            const int kr = krbase + 4 * (m & 1) + 32 * (m >> 1);
            f16x8 a0 = *(const f16x8*)&Kc[kr * 64 + ((hi ^ xl) * 8)];
            f16x8 a1 = *(const f16x8*)&Kc[kr * 64 + (((4 + hi) ^ xl) * 8)];
            f32x4 zA = {0.f, 0.f, 0.f, 0.f};
            zA = __builtin_amdgcn_mfma_f32_16x16x32_f16(a0, qfA0, zA, 0, 0, 0);
            zA = __builtin_amdgcn_mfma_f32_16x16x32_f16(a1, qfA1, zA, 0, 0, 0);
            stA[m] = zA;
            f32x4 zB = {0.f, 0.f, 0.f, 0.f};
            zB = __builtin_amdgcn_mfma_f32_16x16x32_f16(a0, qfB0, zB, 0, 0, 0);
            zB = __builtin_amdgcn_mfma_f32_16x16x32_f16(a1, qfB1, zB, 0, 0, 0);
            stB[m] = zB;
        }
        __builtin_amdgcn_s_setprio(0);

        // --- P = 2^(S') -> bf16 (q pre-scaled by log2e; bare v_exp_f32) ---
        bf16x8 paA0, paA1, paB0, paB1;
        #pragma unroll
        for (int m = 0; m < 4; ++m) {
            __bf16 b0 = (__bf16)exp2v(stA[m][0]);
            __bf16 b1 = (__bf16)exp2v(stA[m][1]);
            __bf16 b2 = (__bf16)exp2v(stA[m][2]);
            __bf16 b3 = (__bf16)exp2v(stA[m][3]);
            if (m == 0)      { paA0[0] = b0; paA0[1] = b1; paA0[2] = b2; paA0[3] = b3; }
            else if (m == 1) { paA0[4] = b0; paA0[5] = b1; paA0[6] = b2; paA0[7] = b3; }
            else if (m == 2) { paA1[0] = b0; paA1[1] = b1; paA1[2] = b2; paA1[3] = b3; }
            else             { paA1[4] = b0; paA1[5] = b1; paA1[6] = b2; paA1[7] = b3; }
        }
        #pragma unroll
        for (int m = 0; m < 4; ++m) {
            __bf16 b0 = (__bf16)exp2v(stB[m][0]);
            __bf16 b1 = (__bf16)exp2v(stB[m][1]);
            __bf16 b2 = (__bf16)exp2v(stB[m][2]);
            __bf16 b3 = (__bf16)exp2v(stB[m][3]);
            if (m == 0)      { paB0[0] = b0; paB0[1] = b1; paB0[2] = b2; paB0[3] = b3; }
            else if (m == 1) { paB0[4] = b0; paB0[5] = b1; paB0[6] = b2; paB0[7] = b3; }
            else if (m == 2) { paB1[0] = b0; paB1[1] = b1; paB1[2] = b2; paB1[3] = b3; }
            else             { paB1[4] = b0; paB1[5] = b1; paB1[6] = b2; paB1[7] = b3; }
        }

        // --- PV + l row-sums (l on the MFMA pipe, keys summed via ones) ---
        __builtin_amdgcn_s_setprio(1);
        laccA4 = __builtin_amdgcn_mfma_f32_16x16x32_bf16(paA0, vone, laccA4, 0, 0, 0);
        laccA4 = __builtin_amdgcn_mfma_f32_16x16x32_bf16(paA1, vone, laccA4, 0, 0, 0);
        laccB4 = __builtin_amdgcn_mfma_f32_16x16x32_bf16(paB0, vone, laccB4, 0, 0, 0);
        laccB4 = __builtin_amdgcn_mfma_f32_16x16x32_bf16(paB1, vone, laccB4, 0, 0, 0);
        #pragma unroll
        for (int nf = 0; nf < 4; ++nf) {
            const int vr = nf * 16 + lo;
            bf16x8 v0 = *(const bf16x8*)&Vc[vr * 64 + ((hi ^ xl) * 8)];
            bf16x8 v1 = *(const bf16x8*)&Vc[vr * 64 + (((4 + hi) ^ xl) * 8)];
            yaccA[nf] = __builtin_amdgcn_mfma_f32_16x16x32_bf16(paA0, v0, yaccA[nf], 0, 0, 0);
            yaccA[nf] = __builtin_amdgcn_mfma_f32_16x16x32_bf16(paA1, v1, yaccA[nf], 0, 0, 0);
            yaccB[nf] = __builtin_amdgcn_mfma_f32_16x16x32_bf16(paB0, v0, yaccB[nf], 0, 0, 0);
            yaccB[nf] = __builtin_amdgcn_mfma_f32_16x16x32_bf16(paB1, v1, yaccB[nf], 0, 0, 0);
        }
        __builtin_amdgcn_s_setprio(0);

        // --- stage tile t+1; prefetch t+2 (within this half's 18 tiles) ---
        if (t + 1 < HTILE) {
            *(uint4*)&Kn[koff0] = ka0; *(uint4*)&Kn[koff1] = ka1;
            *(uint4*)&Vn[voff0] = va0; *(uint4*)&Vn[voff1] = va1;
        }
        if (t + 2 < HTILE) {
            int tb = kq + (t + 2) * 64;
            ka0 = *(const uint4*)(kp + (size_t)(tb + srow0) * DI + sch * 8);
            ka1 = *(const uint4*)(kp + (size_t)(tb + srow1) * DI + sch * 8);
            va0 = *(const uint4*)(vp + (size_t)srow0 * HW + tb + sch * 8);
            va1 = *(const uint4*)(vp + (size_t)srow1 * HW + tb + sch * 8);
        }
        __syncthreads();
    };

    #pragma unroll 1
    for (int tt = 0; tt < HTILE; tt += 2) {
        body(tt,     Kb0, Vb0, Kb1, Vb1);
        body(tt + 1, Kb1, Vb1, Kb0, Vb0);
    }

    // --- finalize: lane already holds l for its D-layout rows q=4hi+r ---
    float invqA[4], invqB[4];
    #pragma unroll
    for (int r = 0; r < 4; ++r) {
        invqA[r] = 1.f / laccA4[r];
        invqB[r] = 1.f / laccB4[r];
    }
    if (lo == 0) {                                // store l for combine weights
        size_t lb = ((size_t)j * NBATCH + n) * HW + P0 + w4 * 32;
        #pragma unroll
        for (int r = 0; r < 4; ++r) {
            lp[lb + 4 * hi + r]      = laccA4[r];
            lp[lb + 16 + 4 * hi + r] = laccB4[r];
        }
    }

    __syncthreads();                              // done with K/V buffers
    u16* yw = smem;                               // [128][72] fp16 restage
    #pragma unroll
    for (int nf = 0; nf < 4; ++nf)
        #pragma unroll
        for (int r = 0; r < 4; ++r) {
            yw[(w4 * 32 + 4 * hi + r) * 72 + nf * 16 + lo]      = f2h(yaccA[nf][r] * invqA[r]);
            yw[(w4 * 32 + 16 + 4 * hi + r) * 72 + nf * 16 + lo] = f2h(yaccB[nf][r] * invqB[r]);
        }
    __syncthreads();

    // --- write partials into combine-block regions of d_out ---
    u32* outb = (u32*)outF + (size_t)n * CCH * HW + (size_t)j * 32 * HW;
    const int ptb = P0 >> 6;
    #pragma unroll
    for (int s = 0; s < 4; ++s) {
        int idx = tid + s * 256;                  // 1024 x 16B chunks
        int T   = idx >> 3, d0 = (idx & 7) * 8;
        int tok = T & 63;
        int f   = (tok >> 1) * HW + (ptb + (T >> 6)) * 64 + (tok & 1) * 32 + (d0 >> 1);
        *(uint4*)&outb[f] = *(const uint4*)&yw[T * 72 + d0];
    }
}

// ---------------------------------------------------------------------------
// Kernel 3: combine 4 partials (2 pass x 2 key-half) + z-projection +
// residual via fp16 MFMA (validated R13).
// ---------------------------------------------------------------------------
__global__ __launch_bounds__(256) void combine_kernel(
    float* __restrict__ outF, const float* __restrict__ lp,
    const u16* __restrict__ Wzf, const float* __restrict__ bz,
    const float* __restrict__ F)
{
    __shared__ __align__(16) float zs[64 * 129];
    const int tid  = threadIdx.x;
    const int n    = blockIdx.x / NTILE;
    const int p0   = (blockIdx.x % NTILE) * 64;
    const int lane = tid & 63, wave = tid >> 6;
    const int lo   = lane & 15, hi = lane >> 4;
    const int tok  = wave * 16 + lo;              // local token (A-frag row)

    const u32* pb = (const u32*)outF + (size_t)n * CCH * HW;
    f16x8 af[4][2];
    #pragma unroll
    for (int jj = 0; jj < 4; ++jj)
        #pragma unroll
        for (int ks = 0; ks < 2; ++ks)
            af[jj][ks] = *(const f16x8*)&pb[(size_t)(jj * 32 + (tok >> 1)) * HW
                                            + p0 + (tok & 1) * 32 + ks * 16 + hi * 4];
    float lw[4];
    #pragma unroll
    for (int jj = 0; jj < 4; ++jj)
        lw[jj] = lp[((size_t)jj * NBATCH + n) * HW + p0 + tok];
    float s0 = 1.f / (lw[0] + lw[1]);
    float s1 = 1.f / (lw[2] + lw[3]);
    _Float16 w00 = (_Float16)(lw[0] * s0), w01 = (_Float16)(lw[1] * s0);
    _Float16 w10 = (_Float16)(lw[2] * s1), w11 = (_Float16)(lw[3] * s1);
    f16x8 a00 = af[0][0] * w00 + af[1][0] * w01;
    f16x8 a01 = af[0][1] * w00 + af[1][1] * w01;
    f16x8 a10 = af[2][0] * w10 + af[3][0] * w11;
    f16x8 a11 = af[2][1] * w10 + af[3][1] * w11;

    f32x4 acc[8];
    #pragma unroll
    for (int g = 0; g < 8; ++g)
        #pragma unroll
        for (int r = 0; r < 4; ++r) acc[g][r] = 0.f;

    #pragma unroll
    for (int g = 0; g < 8; ++g) {
        f16x8 b0 = *(const f16x8*)&Wzf[(size_t)((g * 2 + 0) * 64 + lane) * 8];
        f16x8 b1 = *(const f16x8*)&Wzf[(size_t)((g * 2 + 1) * 64 + lane) * 8];
        acc[g] = __builtin_amdgcn_mfma_f32_16x16x32_f16(a00, b0, acc[g], 0, 0, 0);
        acc[g] = __builtin_amdgcn_mfma_f32_16x16x32_f16(a01, b1, acc[g], 0, 0, 0);
        acc[g] = __builtin_amdgcn_mfma_f32_16x16x32_f16(a10, b0, acc[g], 0, 0, 0);
        acc[g] = __builtin_amdgcn_mfma_f32_16x16x32_f16(a11, b1, acc[g], 0, 0, 0);
    }

    #pragma unroll
    for (int g = 0; g < 8; ++g)
        #pragma unroll
        for (int r = 0; r < 4; ++r)
            zs[(wave * 16 + 4 * hi + r) * 129 + g * 16 + lo] = acc[g][r];
    __syncthreads();

    #pragma unroll 4
    for (int i = 0; i < 32; ++i) {
        int c = wave + 4 * i;
        size_t gi = (size_t)(n * CCH + c) * HW + p0 + lane;
        outF[gi] = zs[lane * 129 + c] + 2.f * bz[c] + F[gi];
    }
}

extern "C" void kernel_launch(void* const* d_in, const int* in_sizes, int n_in,
                              void* d_out, int out_size, void* d_ws, size_t ws_size,
                              hipStream_t stream) {
    const float* F  = (const float*)d_in[0];
    const float* Wq = (const float*)d_in[1];
    const float* bq = (const float*)d_in[2];
    const float* Wk = (const float*)d_in[3];
    const float* bk = (const float*)d_in[4];
    const float* Wv = (const float*)d_in[5];
    const float* bv = (const float*)d_in[6];
    const float* Wz = (const float*)d_in[7];
    const float* bz = (const float*)d_in[8];
    float* outp = (float*)d_out;

    const size_t tok = (size_t)NBATCH * HW * DI;   // 2,359,296 elements
    u16*   qb  = (u16*)d_ws;                       // fp16 (pre-scaled by log2e)
    u16*   kb  = qb  + tok;                        // fp16
    u16*   vtb = kb  + tok;                        // bf16, transposed
    u16*   wf  = vtb + tok;                        // 24576 fp16 frag-ordered Wq/Wk/Wv
    u16*   wzf = wf  + 24576;                      //  8192 fp16 frag-ordered Wz
    float* lpb = (float*)(wzf + 8192);             // 4*16*2304 fp32 l partials
    // total ws: 3*tok*2B + 65KB + 590KB ~= 14.8 MB (partials live in d_out)

    wprep_kernel<<<16, 256, 0, stream>>>(Wq, Wk, Wv, Wz, wf, wzf);
    proj_kernel<<<NBATCH * NTILE, 256, 0, stream>>>(F, wf, bq, bk, bv, qb, kb, vtb);
    attn_pass_kernel<<<4 * NBATCH * QBLK, 256, 0, stream>>>(qb, kb, vtb, outp, lpb);
    combine_kernel<<<NBATCH * NTILE, 256, 0, stream>>>(outp, lpb, wzf, bz, F);
}

// Round 15
// 91.405 us; speedup vs baseline: 1.1890x; 1.1890x over previous
//
#include <hip/hip_runtime.h>
#include <math.h>

// Problem constants (fixed by the reference)
#define NBATCH 16
#define CCH    128     // channels C
#define HW     2304    // 48*48 tokens per frame
#define DI     64      // inter_channels CI
#define NTILE  36      // HW / 64 (proj/combine token blocks)
#define HTILE  18      // key tiles per key-half (attn)
#define QBLK   18      // HW / 128 (attn q-blocks)
#define LOG2E  1.44269504088896f

typedef unsigned short u16;
typedef unsigned int   u32;
typedef __bf16   bf16x8 __attribute__((ext_vector_type(8)));
typedef _Float16 f16x8  __attribute__((ext_vector_type(8)));
typedef float    f32x4  __attribute__((ext_vector_type(4)));

__device__ __forceinline__ u16 f2bf_rne(float x) {
    union { float f; u32 u; } v; v.f = x;
    u32 r = (v.u + 0x7FFFu + ((v.u >> 16) & 1u)) >> 16;
    return (u16)r;
}
__device__ __forceinline__ u16 f2h(float x) {
    union { _Float16 h; u16 u; } c; c.h = (_Float16)x; return c.u;
}
__device__ __forceinline__ float exp2v(float x) {   // bare v_exp_f32: D = 2^S0
    float r;
    asm("v_exp_f32 %0, %1" : "=v"(r) : "v"(x));
    return r;
}

// ---------------------------------------------------------------------------
// Kernel 0: one-time W -> fp16 conversion in MFMA B-frag order (validated R10).
// ---------------------------------------------------------------------------
__global__ __launch_bounds__(256) void wprep_kernel(
    const float* __restrict__ Wq, const float* __restrict__ Wk,
    const float* __restrict__ Wv, const float* __restrict__ Wz,
    u16* __restrict__ Wf, u16* __restrict__ Wzf)
{
    const int idx  = blockIdx.x * 256 + threadIdx.x;   // 0..4095
    if (idx < 3072) {
        const int lane = idx & 63;
        const int fi   = idx >> 6;
        const int g = fi >> 2, ks = fi & 3;
        const int lo = lane & 15, hi = lane >> 4;
        const int row = g * 16 + lo;
        const float* src = (row < 64)  ? &Wq[row * CCH]
                         : (row < 128) ? &Wk[(row - 64) * CCH]
                                       : &Wv[(row - 128) * CCH];
        const int c0 = (ks * 4 + hi) * 8;
        float4 a = *(const float4*)&src[c0];
        float4 b = *(const float4*)&src[c0 + 4];
        union { u16 s8[8]; uint4 v; } pk;
        pk.s8[0] = f2h(a.x); pk.s8[1] = f2h(a.y); pk.s8[2] = f2h(a.z); pk.s8[3] = f2h(a.w);
        pk.s8[4] = f2h(b.x); pk.s8[5] = f2h(b.y); pk.s8[6] = f2h(b.z); pk.s8[7] = f2h(b.w);
        *(uint4*)&Wf[(size_t)idx * 8] = pk.v;
    } else {
        const int t    = idx - 3072;
        const int lane = t & 63;
        const int fi   = t >> 6;
        const int g = fi >> 1, ks = fi & 1;
        const int lo = lane & 15, hi = lane >> 4;
        const int row = g * 16 + lo;
        const int d0  = ks * 32 + hi * 8;
        float4 a = *(const float4*)&Wz[row * DI + d0];
        float4 b = *(const float4*)&Wz[row * DI + d0 + 4];
        union { u16 s8[8]; uint4 v; } pk;
        pk.s8[0] = f2h(a.x); pk.s8[1] = f2h(a.y); pk.s8[2] = f2h(a.z); pk.s8[3] = f2h(a.w);
        pk.s8[4] = f2h(b.x); pk.s8[5] = f2h(b.y); pk.s8[6] = f2h(b.z); pk.s8[7] = f2h(b.w);
        *(uint4*)&Wzf[(size_t)t * 8] = pk.v;
    }
}

// ---------------------------------------------------------------------------
// Kernel 1: q/k/v projection fp16 MFMA GEMM (validated R7/R9/R10).
// q pre-scaled by log2(e) so attn uses bare v_exp_f32 (validated R14).
// ---------------------------------------------------------------------------
__global__ __launch_bounds__(256) void proj_kernel(
    const float* __restrict__ F, const u16* __restrict__ Wf,
    const float* __restrict__ bq, const float* __restrict__ bk,
    const float* __restrict__ bv,
    u16* __restrict__ qo, u16* __restrict__ ko, u16* __restrict__ vto)
{
    __shared__ __align__(16) u16 Fl[64 * 128];
    __shared__ __align__(16) u16 Vt[64 * 72];

    const int tid  = threadIdx.x;
    const int n    = blockIdx.x / NTILE;
    const int p0   = (blockIdx.x % NTILE) * 64;
    const int lane = tid & 63, wave = tid >> 6;
    const int lo   = lane & 15, hi = lane >> 4;

    const float* Fn = F + (size_t)n * CCH * HW;
    #pragma unroll
    for (int i = 0; i < 4; ++i) {
        int s  = tid + i * 256;
        int c0 = (s >> 4) * 2;
        int t0 = (s & 15) * 4;
        const float* fp_ = &Fn[(size_t)c0 * HW + p0 + t0];
        float4 fa = *(const float4*)fp_;
        float4 fb = *(const float4*)(fp_ + HW);
        #pragma unroll
        for (int e = 0; e < 4; ++e) {
            int t = t0 + e;
            u32 w = (u32)f2h((&fa.x)[e]) | ((u32)f2h((&fb.x)[e]) << 16);
            *(u32*)&Fl[t * 128 + (((c0 >> 3) ^ (t & 15)) << 3) + (c0 & 7)] = w;
        }
    }
    __syncthreads();

    const int arow = wave * 16 + lo;
    f16x8 af[4];
    #pragma unroll
    for (int ks = 0; ks < 4; ++ks)
        af[ks] = *(const f16x8*)&Fl[arow * 128 + (((ks * 4 + hi) ^ lo) << 3)];

    f32x4 acc[12];
    #pragma unroll
    for (int g = 0; g < 12; ++g)
        #pragma unroll
        for (int r = 0; r < 4; ++r) acc[g][r] = 0.f;

    #pragma unroll
    for (int g = 0; g < 12; ++g) {
        #pragma unroll
        for (int ks = 0; ks < 4; ++ks) {
            f16x8 bf = *(const f16x8*)&Wf[(size_t)((g * 4 + ks) * 64 + lane) * 8];
            acc[g] = __builtin_amdgcn_mfma_f32_16x16x32_f16(af[ks], bf, acc[g], 0, 0, 0);
        }
    }

    const int twb = p0 + wave * 16 + 4 * hi;
    #pragma unroll
    for (int g = 0; g < 4; ++g) {
        float bQ = bq[g * 16 + lo], bK = bk[g * 16 + lo];
        #pragma unroll
        for (int r = 0; r < 4; ++r) {
            size_t off = ((size_t)n * HW + twb + r) * DI + g * 16 + lo;
            qo[off] = f2h((acc[g][r] + bQ) * LOG2E);   // exp2 pre-scale
            ko[off] = f2h(acc[g + 4][r] + bK);
        }
    }
    #pragma unroll
    for (int g = 0; g < 4; ++g) {
        float bV = bv[g * 16 + lo];
        #pragma unroll
        for (int r = 0; r < 4; ++r)
            Vt[(g * 16 + lo) * 72 + wave * 16 + 4 * hi + r] = f2bf_rne(acc[g + 8][r] + bV);
    }
    __syncthreads();
    #pragma unroll
    for (int i = 0; i < 2; ++i) {
        int s = tid + i * 256;
        int d = s >> 3, c8 = (s & 7) * 8;
        *(uint4*)&vto[((size_t)n * DI + d) * HW + p0 + c8] = *(const uint4*)&Vt[d * 72 + c8];
    }
}

// ---------------------------------------------------------------------------
// Kernel 2: flash attention (R13 structure + R14 VALU diet).
// R14's regression was __launch_bounds__(256,4): toolchain resolved it to a
// 64-VGPR cap -> spills (WRITE_SIZE 45 MB). Bare (256) gives VGPR~112,
// no spills (R13-verified). Diet kept: P = 2^(S') via bare v_exp_f32
// (q pre-scaled), l row-sums on the MFMA pipe via ones-B-frag.
// ---------------------------------------------------------------------------
__global__ __launch_bounds__(256) void attn_pass_kernel(
    const u16* __restrict__ q, const u16* __restrict__ k, const u16* __restrict__ vt,
    float* __restrict__ outF, float* __restrict__ lp)
{
    __shared__ __align__(16) u16 smem[16384];     // 32 KiB
    u16* const Kb0 = smem;
    u16* const Kb1 = smem + 4096;
    u16* const Vb0 = smem + 8192;
    u16* const Vb1 = smem + 12288;

    const int tid  = threadIdx.x;
    const int lane = tid & 63;
    const int w4   = tid >> 6;                    // 0..3
    const int lo   = lane & 15, hi = lane >> 4;

    // chunked bijective XCD swizzle: 1152 = 8 * 144
    const int bid  = (int)blockIdx.x;
    const int w    = (bid & 7) * 144 + (bid >> 3);
    const int j    = w / (NBATCH * QBLK);         // pass*2 + half
    const int rem  = w % (NBATCH * QBLK);
    const int n    = rem / QBLK;
    const int qb   = rem % QBLK;
    const int pass = j >> 1, half = j & 1;
    const int P0   = qb * 128;

    const int nb = (pass == 0) ? (n > 0 ? n - 1 : 0)
                               : (n < NBATCH - 1 ? n + 1 : n);
    const u16* kp = k  + (size_t)nb * HW * DI;
    const u16* vp = vt + (size_t)nb * DI * HW;
    const int  kq = half * (HTILE * 64);          // this half's key offset

    // Q fragments (B-operand of swapped QK), two 16-row sets per wave
    f16x8 qfA0, qfA1, qfB0, qfB1;
    {
        const u16* qp = q + ((size_t)n * HW + P0 + w4 * 32 + lo) * DI + hi * 8;
        qfA0 = *(const f16x8*)qp;
        qfA1 = *(const f16x8*)(qp + 32);
        qfB0 = *(const f16x8*)(qp + 16 * DI);
        qfB1 = *(const f16x8*)(qp + 16 * DI + 32);
    }

    // ones B-frag for the l row-sum MFMA
    bf16x8 vone;
    #pragma unroll
    for (int e = 0; e < 8; ++e) vone[e] = (__bf16)1.0f;

    // staging geometry: 512 x 16B chunks per 8KB tile; thread covers 2 rows
    const int sch   = tid & 7;
    const int srow0 = tid >> 3;
    const int srow1 = srow0 + 32;
    const int fk0   = (srow0 & 3) | ((srow0 & 8) >> 1);
    const int fk1   = (srow1 & 3) | ((srow1 & 8) >> 1);
    const int koff0 = srow0 * 64 + ((sch ^ fk0) * 8);
    const int koff1 = srow1 * 64 + ((sch ^ fk1) * 8);
    const int voff0 = srow0 * 64 + ((sch ^ (srow0 & 7)) * 8);
    const int voff1 = srow1 * 64 + ((sch ^ (srow1 & 7)) * 8);

    // permuted K A-frag row base: kr_m = krbase + 4*(m&1) + 32*(m>>1)
    const int krbase = 8 * (lo >> 2) + (lo & 3);
    const int xl = lo & 7;

    f32x4 yaccA[4], yaccB[4], laccA4, laccB4;
    #pragma unroll
    for (int nf = 0; nf < 4; ++nf)
        #pragma unroll
        for (int r = 0; r < 4; ++r) { yaccA[nf][r] = 0.f; yaccB[nf][r] = 0.f; }
    #pragma unroll
    for (int r = 0; r < 4; ++r) { laccA4[r] = 0.f; laccB4[r] = 0.f; }

    // prologue: tile0 -> buf0; tile1 -> regs
    uint4 ka0 = *(const uint4*)(kp + (size_t)(kq + srow0) * DI + sch * 8);
    uint4 ka1 = *(const uint4*)(kp + (size_t)(kq + srow1) * DI + sch * 8);
    uint4 va0 = *(const uint4*)(vp + (size_t)srow0 * HW + kq + sch * 8);
    uint4 va1 = *(const uint4*)(vp + (size_t)srow1 * HW + kq + sch * 8);
    *(uint4*)&Kb0[koff0] = ka0;  *(uint4*)&Kb0[koff1] = ka1;
    *(uint4*)&Vb0[voff0] = va0;  *(uint4*)&Vb0[voff1] = va1;
    ka0 = *(const uint4*)(kp + (size_t)(kq + 64 + srow0) * DI + sch * 8);
    ka1 = *(const uint4*)(kp + (size_t)(kq + 64 + srow1) * DI + sch * 8);
    va0 = *(const uint4*)(vp + (size_t)srow0 * HW + kq + 64 + sch * 8);
    va1 = *(const uint4*)(vp + (size_t)srow1 * HW + kq + 64 + sch * 8);
    __syncthreads();

    auto body = [&](int t, const u16* Kc, const u16* Vc, u16* Kn, u16* Vn) {
        // --- swapped QK^T with permuted A rows (both q-sets share K frags) ---
        f32x4 stA[4], stB[4];
        __builtin_amdgcn_s_setprio(1);
        #pragma unroll
        for (int m = 0; m < 4; ++m) {
            const int kr = krbase + 4 * (m & 1) + 32 * (m >> 1);
            f16x8 a0 = *(const f16x8*)&Kc[kr * 64 + ((hi ^ xl) * 8)];
            f16x8 a1 = *(const f16x8*)&Kc[kr * 64 + (((4 + hi) ^ xl) * 8)];
            f32x4 zA = {0.f, 0.f, 0.f, 0.f};
            zA = __builtin_amdgcn_mfma_f32_16x16x32_f16(a0, qfA0, zA, 0, 0, 0);
            zA = __builtin_amdgcn_mfma_f32_16x16x32_f16(a1, qfA1, zA, 0, 0, 0);
            stA[m] = zA;
            f32x4 zB = {0.f, 0.f, 0.f, 0.f};
            zB = __builtin_amdgcn_mfma_f32_16x16x32_f16(a0, qfB0, zB, 0, 0, 0);
            zB = __builtin_amdgcn_mfma_f32_16x16x32_f16(a1, qfB1, zB, 0, 0, 0);
            stB[m] = zB;
        }
        __builtin_amdgcn_s_setprio(0);

        // --- P = 2^(S') -> bf16 (q pre-scaled by log2e; bare v_exp_f32) ---
        bf16x8 paA0, paA1, paB0, paB1;
        #pragma unroll
        for (int m = 0; m < 4; ++m) {
            __bf16 b0 = (__bf16)exp2v(stA[m][0]);
            __bf16 b1 = (__bf16)exp2v(stA[m][1]);
            __bf16 b2 = (__bf16)exp2v(stA[m][2]);
            __bf16 b3 = (__bf16)exp2v(stA[m][3]);
            if (m == 0)      { paA0[0] = b0; paA0[1] = b1; paA0[2] = b2; paA0[3] = b3; }
            else if (m == 1) { paA0[4] = b0; paA0[5] = b1; paA0[6] = b2; paA0[7] = b3; }
            else if (m == 2) { paA1[0] = b0; paA1[1] = b1; paA1[2] = b2; paA1[3] = b3; }
            else             { paA1[4] = b0; paA1[5] = b1; paA1[6] = b2; paA1[7] = b3; }
        }
        #pragma unroll
        for (int m = 0; m < 4; ++m) {
            __bf16 b0 = (__bf16)exp2v(stB[m][0]);
            __bf16 b1 = (__bf16)exp2v(stB[m][1]);
            __bf16 b2 = (__bf16)exp2v(stB[m][2]);
            __bf16 b3 = (__bf16)exp2v(stB[m][3]);
            if (m == 0)      { paB0[0] = b0; paB0[1] = b1; paB0[2] = b2; paB0[3] = b3; }
            else if (m == 1) { paB0[4] = b0; paB0[5] = b1; paB0[6] = b2; paB0[7] = b3; }
            else if (m == 2) { paB1[0] = b0; paB1[1] = b1; paB1[2] = b2; paB1[3] = b3; }
            else             { paB1[4] = b0; paB1[5] = b1; paB1[6] = b2; paB1[7] = b3; }
        }

        // --- PV + l row-sums (l on the MFMA pipe, keys summed via ones) ---
        __builtin_amdgcn_s_setprio(1);
        laccA4 = __builtin_amdgcn_mfma_f32_16x16x32_bf16(paA0, vone, laccA4, 0, 0, 0);
        laccA4 = __builtin_amdgcn_mfma_f32_16x16x32_bf16(paA1, vone, laccA4, 0, 0, 0);
        laccB4 = __builtin_amdgcn_mfma_f32_16x16x32_bf16(paB0, vone, laccB4, 0, 0, 0);
        laccB4 = __builtin_amdgcn_mfma_f32_16x16x32_bf16(paB1, vone, laccB4, 0, 0, 0);
        #pragma unroll
        for (int nf = 0; nf < 4; ++nf) {
            const int vr = nf * 16 + lo;
            bf16x8 v0 = *(const bf16x8*)&Vc[vr * 64 + ((hi ^ xl) * 8)];
            bf16x8 v1 = *(const bf16x8*)&Vc[vr * 64 + (((4 + hi) ^ xl) * 8)];
            yaccA[nf] = __builtin_amdgcn_mfma_f32_16x16x32_bf16(paA0, v0, yaccA[nf], 0, 0, 0);
            yaccA[nf] = __builtin_amdgcn_mfma_f32_16x16x32_bf16(paA1, v1, yaccA[nf], 0, 0, 0);
            yaccB[nf] = __builtin_amdgcn_mfma_f32_16x16x32_bf16(paB0, v0, yaccB[nf], 0, 0, 0);
            yaccB[nf] = __builtin_amdgcn_mfma_f32_16x16x32_bf16(paB1, v1, yaccB[nf], 0, 0, 0);
        }
        __builtin_amdgcn_s_setprio(0);

        // --- stage tile t+1; prefetch t+2 (within this half's 18 tiles) ---
        if (t + 1 < HTILE) {
            *(uint4*)&Kn[koff0] = ka0; *(uint4*)&Kn[koff1] = ka1;
            *(uint4*)&Vn[voff0] = va0; *(uint4*)&Vn[voff1] = va1;
        }
        if (t + 2 < HTILE) {
            int tb = kq + (t + 2) * 64;
            ka0 = *(const uint4*)(kp + (size_t)(tb + srow0) * DI + sch * 8);
            ka1 = *(const uint4*)(kp + (size_t)(tb + srow1) * DI + sch * 8);
            va0 = *(const uint4*)(vp + (size_t)srow0 * HW + tb + sch * 8);
            va1 = *(const uint4*)(vp + (size_t)srow1 * HW + tb + sch * 8);
        }
        __syncthreads();
    };

    #pragma unroll 1
    for (int tt = 0; tt < HTILE; tt += 2) {
        body(tt,     Kb0, Vb0, Kb1, Vb1);
        body(tt + 1, Kb1, Vb1, Kb0, Vb0);
    }

    // --- finalize: lane already holds l for its D-layout rows q=4hi+r ---
    float invqA[4], invqB[4];
    #pragma unroll
    for (int r = 0; r < 4; ++r) {
        invqA[r] = 1.f / laccA4[r];
        invqB[r] = 1.f / laccB4[r];
    }
    if (lo == 0) {                                // store l for combine weights
        size_t lb = ((size_t)j * NBATCH + n) * HW + P0 + w4 * 32;
        #pragma unroll
        for (int r = 0; r < 4; ++r) {
            lp[lb + 4 * hi + r]      = laccA4[r];
            lp[lb + 16 + 4 * hi + r] = laccB4[r];
        }
    }

    __syncthreads();                              // done with K/V buffers
    u16* yw = smem;                               // [128][72] fp16 restage
    #pragma unroll
    for (int nf = 0; nf < 4; ++nf)
        #pragma unroll
        for (int r = 0; r < 4; ++r) {
            yw[(w4 * 32 + 4 * hi + r) * 72 + nf * 16 + lo]      = f2h(yaccA[nf][r] * invqA[r]);
            yw[(w4 * 32 + 16 + 4 * hi + r) * 72 + nf * 16 + lo] = f2h(yaccB[nf][r] * invqB[r]);
        }
    __syncthreads();

    // --- write partials into combine-block regions of d_out ---
    u32* outb = (u32*)outF + (size_t)n * CCH * HW + (size_t)j * 32 * HW;
    const int ptb = P0 >> 6;
    #pragma unroll
    for (int s = 0; s < 4; ++s) {
        int idx = tid + s * 256;                  // 1024 x 16B chunks
        int T   = idx >> 3, d0 = (idx & 7) * 8;
        int tok = T & 63;
        int f   = (tok >> 1) * HW + (ptb + (T >> 6)) * 64 + (tok & 1) * 32 + (d0 >> 1);
        *(uint4*)&outb[f] = *(const uint4*)&yw[T * 72 + d0];
    }
}

// ---------------------------------------------------------------------------
// Kernel 3: combine 4 partials (2 pass x 2 key-half) + z-projection +
// residual via fp16 MFMA (validated R13).
// ---------------------------------------------------------------------------
__global__ __launch_bounds__(256) void combine_kernel(
    float* __restrict__ outF, const float* __restrict__ lp,
    const u16* __restrict__ Wzf, const float* __restrict__ bz,
    const float* __restrict__ F)
{
    __shared__ __align__(16) float zs[64 * 129];
    const int tid  = threadIdx.x;
    const int n    = blockIdx.x / NTILE;
    const int p0   = (blockIdx.x % NTILE) * 64;
    const int lane = tid & 63, wave = tid >> 6;
    const int lo   = lane & 15, hi = lane >> 4;
    const int tok  = wave * 16 + lo;              // local token (A-frag row)

    const u32* pb = (const u32*)outF + (size_t)n * CCH * HW;
    f16x8 af[4][2];
    #pragma unroll
    for (int jj = 0; jj < 4; ++jj)
        #pragma unroll
        for (int ks = 0; ks < 2; ++ks)
            af[jj][ks] = *(const f16x8*)&pb[(size_t)(jj * 32 + (tok >> 1)) * HW
                                            + p0 + (tok & 1) * 32 + ks * 16 + hi * 4];
    float lw[4];
    #pragma unroll
    for (int jj = 0; jj < 4; ++jj)
        lw[jj] = lp[((size_t)jj * NBATCH + n) * HW + p0 + tok];
    float s0 = 1.f / (lw[0] + lw[1]);
    float s1 = 1.f / (lw[2] + lw[3]);
    _Float16 w00 = (_Float16)(lw[0] * s0), w01 = (_Float16)(lw[1] * s0);
    _Float16 w10 = (_Float16)(lw[2] * s1), w11 = (_Float16)(lw[3] * s1);
    f16x8 a00 = af[0][0] * w00 + af[1][0] * w01;
    f16x8 a01 = af[0][1] * w00 + af[1][1] * w01;
    f16x8 a10 = af[2][0] * w10 + af[3][0] * w11;
    f16x8 a11 = af[2][1] * w10 + af[3][1] * w11;

    f32x4 acc[8];
    #pragma unroll
    for (int g = 0; g < 8; ++g)
        #pragma unroll
        for (int r = 0; r < 4; ++r) acc[g][r] = 0.f;

    #pragma unroll
    for (int g = 0; g < 8; ++g) {
        f16x8 b0 = *(const f16x8*)&Wzf[(size_t)((g * 2 + 0) * 64 + lane) * 8];
        f16x8 b1 = *(const f16x8*)&Wzf[(size_t)((g * 2 + 1) * 64 + lane) * 8];
        acc[g] = __builtin_amdgcn_mfma_f32_16x16x32_f16(a00, b0, acc[g], 0, 0, 0);
        acc[g] = __builtin_amdgcn_mfma_f32_16x16x32_f16(a01, b1, acc[g], 0, 0, 0);
        acc[g] = __builtin_amdgcn_mfma_f32_16x16x32_f16(a10, b0, acc[g], 0, 0, 0);
        acc[g] = __builtin_amdgcn_mfma_f32_16x16x32_f16(a11, b1, acc[g], 0, 0, 0);
    }

    #pragma unroll
    for (int g = 0; g < 8; ++g)
        #pragma unroll
        for (int r = 0; r < 4; ++r)
            zs[(wave * 16 + 4 * hi + r) * 129 + g * 16 + lo] = acc[g][r];
    __syncthreads();

    #pragma unroll 4
    for (int i = 0; i < 32; ++i) {
        int c = wave + 4 * i;
        size_t gi = (size_t)(n * CCH + c) * HW + p0 + lane;
        outF[gi] = zs[lane * 129 + c] + 2.f * bz[c] + F[gi];
    }
}

extern "C" void kernel_launch(void* const* d_in, const int* in_sizes, int n_in,
                              void* d_out, int out_size, void* d_ws, size_t ws_size,
                              hipStream_t stream) {
    const float* F  = (const float*)d_in[0];
    const float* Wq = (const float*)d_in[1];
    const float* bq = (const float*)d_in[2];
    const float* Wk = (const float*)d_in[3];
    const float* bk = (const float*)d_in[4];
    const float* Wv = (const float*)d_in[5];
    const float* bv = (const float*)d_in[6];
    const float* Wz = (const float*)d_in[7];
    const float* bz = (const float*)d_in[8];
    float* outp = (float*)d_out;

    const size_t tok = (size_t)NBATCH * HW * DI;   // 2,359,296 elements
    u16*   qb  = (u16*)d_ws;                       // fp16 (pre-scaled by log2e)
    u16*   kb  = qb  + tok;                        // fp16
    u16*   vtb = kb  + tok;                        // bf16, transposed
    u16*   wf  = vtb + tok;                        // 24576 fp16 frag-ordered Wq/Wk/Wv
    u16*   wzf = wf  + 24576;                      //  8192 fp16 frag-ordered Wz
    float* lpb = (float*)(wzf + 8192);             // 4*16*2304 fp32 l partials
    // total ws: 3*tok*2B + 65KB + 590KB ~= 14.8 MB (partials live in d_out)

    wprep_kernel<<<16, 256, 0, stream>>>(Wq, Wk, Wv, Wz, wf, wzf);
    proj_kernel<<<NBATCH * NTILE, 256, 0, stream>>>(F, wf, bq, bk, bv, qb, kb, vtb);
    attn_pass_kernel<<<4 * NBATCH * QBLK, 256, 0, stream>>>(qb, kb, vtb, outp, lpb);
    combine_kernel<<<NBATCH * NTILE, 256, 0, stream>>>(outp, lpb, wzf, bz, F);
}

// Round 16
// 89.855 us; speedup vs baseline: 1.2095x; 1.0173x over previous
//
#include <hip/hip_runtime.h>
#include <math.h>

// Problem constants (fixed by the reference)
#define NBATCH 16
#define CCH    128     // channels C
#define HW     2304    // 48*48 tokens per frame
#define DI     64      // inter_channels CI
#define NTILE  36      // HW / 64 (proj/combine token blocks)
#define HTILE  18      // key tiles per key-half (attn)
#define QBLK   18      // HW / 128 (attn q-blocks)
#define LOG2E  1.44269504088896f

typedef unsigned short u16;
typedef unsigned int   u32;
typedef __bf16   bf16x8 __attribute__((ext_vector_type(8)));
typedef _Float16 f16x8  __attribute__((ext_vector_type(8)));
typedef float    f32x4  __attribute__((ext_vector_type(4)));

__device__ __forceinline__ u16 f2bf_rne(float x) {
    union { float f; u32 u; } v; v.f = x;
    u32 r = (v.u + 0x7FFFu + ((v.u >> 16) & 1u)) >> 16;
    return (u16)r;
}
__device__ __forceinline__ u16 f2h(float x) {
    union { _Float16 h; u16 u; } c; c.h = (_Float16)x; return c.u;
}
__device__ __forceinline__ float exp2v(float x) {   // bare v_exp_f32: D = 2^S0
    float r;
    asm("v_exp_f32 %0, %1" : "=v"(r) : "v"(x));
    return r;
}

// ---------------------------------------------------------------------------
// Kernel 0: one-time W -> fp16 conversion in MFMA B-frag order (validated R10).
// ---------------------------------------------------------------------------
__global__ __launch_bounds__(256) void wprep_kernel(
    const float* __restrict__ Wq, const float* __restrict__ Wk,
    const float* __restrict__ Wv, const float* __restrict__ Wz,
    u16* __restrict__ Wf, u16* __restrict__ Wzf)
{
    const int idx  = blockIdx.x * 256 + threadIdx.x;   // 0..4095
    if (idx < 3072) {
        const int lane = idx & 63;
        const int fi   = idx >> 6;
        const int g = fi >> 2, ks = fi & 3;
        const int lo = lane & 15, hi = lane >> 4;
        const int row = g * 16 + lo;
        const float* src = (row < 64)  ? &Wq[row * CCH]
                         : (row < 128) ? &Wk[(row - 64) * CCH]
                                       : &Wv[(row - 128) * CCH];
        const int c0 = (ks * 4 + hi) * 8;
        float4 a = *(const float4*)&src[c0];
        float4 b = *(const float4*)&src[c0 + 4];
        union { u16 s8[8]; uint4 v; } pk;
        pk.s8[0] = f2h(a.x); pk.s8[1] = f2h(a.y); pk.s8[2] = f2h(a.z); pk.s8[3] = f2h(a.w);
        pk.s8[4] = f2h(b.x); pk.s8[5] = f2h(b.y); pk.s8[6] = f2h(b.z); pk.s8[7] = f2h(b.w);
        *(uint4*)&Wf[(size_t)idx * 8] = pk.v;
    } else {
        const int t    = idx - 3072;
        const int lane = t & 63;
        const int fi   = t >> 6;
        const int g = fi >> 1, ks = fi & 1;
        const int lo = lane & 15, hi = lane >> 4;
        const int row = g * 16 + lo;
        const int d0  = ks * 32 + hi * 8;
        float4 a = *(const float4*)&Wz[row * DI + d0];
        float4 b = *(const float4*)&Wz[row * DI + d0 + 4];
        union { u16 s8[8]; uint4 v; } pk;
        pk.s8[0] = f2h(a.x); pk.s8[1] = f2h(a.y); pk.s8[2] = f2h(a.z); pk.s8[3] = f2h(a.w);
        pk.s8[4] = f2h(b.x); pk.s8[5] = f2h(b.y); pk.s8[6] = f2h(b.z); pk.s8[7] = f2h(b.w);
        *(uint4*)&Wzf[(size_t)t * 8] = pk.v;
    }
}

// ---------------------------------------------------------------------------
// Kernel 1: q/k/v projection fp16 MFMA GEMM (validated R7/R9/R10).
// q pre-scaled by log2(e) so attn uses bare v_exp_f32 (validated R14/R15).
// ---------------------------------------------------------------------------
__global__ __launch_bounds__(256) void proj_kernel(
    const float* __restrict__ F, const u16* __restrict__ Wf,
    const float* __restrict__ bq, const float* __restrict__ bk,
    const float* __restrict__ bv,
    u16* __restrict__ qo, u16* __restrict__ ko, u16* __restrict__ vto)
{
    __shared__ __align__(16) u16 Fl[64 * 128];
    __shared__ __align__(16) u16 Vt[64 * 72];

    const int tid  = threadIdx.x;
    const int n    = blockIdx.x / NTILE;
    const int p0   = (blockIdx.x % NTILE) * 64;
    const int lane = tid & 63, wave = tid >> 6;
    const int lo   = lane & 15, hi = lane >> 4;

    const float* Fn = F + (size_t)n * CCH * HW;
    #pragma unroll
    for (int i = 0; i < 4; ++i) {
        int s  = tid + i * 256;
        int c0 = (s >> 4) * 2;
        int t0 = (s & 15) * 4;
        const float* fp_ = &Fn[(size_t)c0 * HW + p0 + t0];
        float4 fa = *(const float4*)fp_;
        float4 fb = *(const float4*)(fp_ + HW);
        #pragma unroll
        for (int e = 0; e < 4; ++e) {
            int t = t0 + e;
            u32 w = (u32)f2h((&fa.x)[e]) | ((u32)f2h((&fb.x)[e]) << 16);
            *(u32*)&Fl[t * 128 + (((c0 >> 3) ^ (t & 15)) << 3) + (c0 & 7)] = w;
        }
    }
    __syncthreads();

    const int arow = wave * 16 + lo;
    f16x8 af[4];
    #pragma unroll
    for (int ks = 0; ks < 4; ++ks)
        af[ks] = *(const f16x8*)&Fl[arow * 128 + (((ks * 4 + hi) ^ lo) << 3)];

    f32x4 acc[12];
    #pragma unroll
    for (int g = 0; g < 12; ++g)
        #pragma unroll
        for (int r = 0; r < 4; ++r) acc[g][r] = 0.f;

    #pragma unroll
    for (int g = 0; g < 12; ++g) {
        #pragma unroll
        for (int ks = 0; ks < 4; ++ks) {
            f16x8 bf = *(const f16x8*)&Wf[(size_t)((g * 4 + ks) * 64 + lane) * 8];
            acc[g] = __builtin_amdgcn_mfma_f32_16x16x32_f16(af[ks], bf, acc[g], 0, 0, 0);
        }
    }

    const int twb = p0 + wave * 16 + 4 * hi;
    #pragma unroll
    for (int g = 0; g < 4; ++g) {
        float bQ = bq[g * 16 + lo], bK = bk[g * 16 + lo];
        #pragma unroll
        for (int r = 0; r < 4; ++r) {
            size_t off = ((size_t)n * HW + twb + r) * DI + g * 16 + lo;
            qo[off] = f2h((acc[g][r] + bQ) * LOG2E);   // exp2 pre-scale
            ko[off] = f2h(acc[g + 4][r] + bK);
        }
    }
    #pragma unroll
    for (int g = 0; g < 4; ++g) {
        float bV = bv[g * 16 + lo];
        #pragma unroll
        for (int r = 0; r < 4; ++r)
            Vt[(g * 16 + lo) * 72 + wave * 16 + 4 * hi + r] = f2bf_rne(acc[g + 8][r] + bV);
    }
    __syncthreads();
    #pragma unroll
    for (int i = 0; i < 2; ++i) {
        int s = tid + i * 256;
        int d = s >> 3, c8 = (s & 7) * 8;
        *(uint4*)&vto[((size_t)n * DI + d) * HW + p0 + c8] = *(const uint4*)&Vt[d * 72 + c8];
    }
}

// ---------------------------------------------------------------------------
// Kernel 2: flash attention (R13 structure + R14/R15 VALU diet).
// This round (T14 issue-early): the t+1 LDS write and t+2 global-load issue
// move from the END of the body to the TOP. R15 issued the t+2 loads ~10
// instructions before __syncthreads, so the compiler's mandatory vmcnt(0)
// barrier-drain ate the full ~200cyc L2 latency every tile. Issued at the
// top, the loads have the whole QK+exp+PV body to land -> drain ~free.
// Race-safety unchanged: the barrier at the end of body(t-1) guarantees all
// waves finished READING buf^1 before any wave WRITES it at the top of
// body(t) (same argument as R13's end-of-body position).
// NOTE: bare __launch_bounds__(256) — the 2-arg form caps VGPR at 64 and
// spills (R11/R14 regressions). VGPR ~96 here, no spills.
// ---------------------------------------------------------------------------
__global__ __launch_bounds__(256) void attn_pass_kernel(
    const u16* __restrict__ q, const u16* __restrict__ k, const u16* __restrict__ vt,
    float* __restrict__ outF, float* __restrict__ lp)
{
    __shared__ __align__(16) u16 smem[16384];     // 32 KiB
    u16* const Kb0 = smem;
    u16* const Kb1 = smem + 4096;
    u16* const Vb0 = smem + 8192;
    u16* const Vb1 = smem + 12288;

    const int tid  = threadIdx.x;
    const int lane = tid & 63;
    const int w4   = tid >> 6;                    // 0..3
    const int lo   = lane & 15, hi = lane >> 4;

    // chunked bijective XCD swizzle: 1152 = 8 * 144
    const int bid  = (int)blockIdx.x;
    const int w    = (bid & 7) * 144 + (bid >> 3);
    const int j    = w / (NBATCH * QBLK);         // pass*2 + half
    const int rem  = w % (NBATCH * QBLK);
    const int n    = rem / QBLK;
    const int qb   = rem % QBLK;
    const int pass = j >> 1, half = j & 1;
    const int P0   = qb * 128;

    const int nb = (pass == 0) ? (n > 0 ? n - 1 : 0)
                               : (n < NBATCH - 1 ? n + 1 : n);
    const u16* kp = k  + (size_t)nb * HW * DI;
    const u16* vp = vt + (size_t)nb * DI * HW;
    const int  kq = half * (HTILE * 64);          // this half's key offset

    // Q fragments (B-operand of swapped QK), two 16-row sets per wave
    f16x8 qfA0, qfA1, qfB0, qfB1;
    {
        const u16* qp = q + ((size_t)n * HW + P0 + w4 * 32 + lo) * DI + hi * 8;
        qfA0 = *(const f16x8*)qp;
        qfA1 = *(const f16x8*)(qp + 32);
        qfB0 = *(const f16x8*)(qp + 16 * DI);
        qfB1 = *(const f16x8*)(qp + 16 * DI + 32);
    }

    // ones B-frag for the l row-sum MFMA
    bf16x8 vone;
    #pragma unroll
    for (int e = 0; e < 8; ++e) vone[e] = (__bf16)1.0f;

    // staging geometry: 512 x 16B chunks per 8KB tile; thread covers 2 rows
    const int sch   = tid & 7;
    const int srow0 = tid >> 3;
    const int srow1 = srow0 + 32;
    const int fk0   = (srow0 & 3) | ((srow0 & 8) >> 1);
    const int fk1   = (srow1 & 3) | ((srow1 & 8) >> 1);
    const int koff0 = srow0 * 64 + ((sch ^ fk0) * 8);
    const int koff1 = srow1 * 64 + ((sch ^ fk1) * 8);
    const int voff0 = srow0 * 64 + ((sch ^ (srow0 & 7)) * 8);
    const int voff1 = srow1 * 64 + ((sch ^ (srow1 & 7)) * 8);

    // permuted K A-frag row base: kr_m = krbase + 4*(m&1) + 32*(m>>1)
    const int krbase = 8 * (lo >> 2) + (lo & 3);
    const int xl = lo & 7;

    f32x4 yaccA[4], yaccB[4], laccA4, laccB4;
    #pragma unroll
    for (int nf = 0; nf < 4; ++nf)
        #pragma unroll
        for (int r = 0; r < 4; ++r) { yaccA[nf][r] = 0.f; yaccB[nf][r] = 0.f; }
    #pragma unroll
    for (int r = 0; r < 4; ++r) { laccA4[r] = 0.f; laccB4[r] = 0.f; }

    // prologue: tile0 -> buf0; tile1 -> regs
    uint4 ka0 = *(const uint4*)(kp + (size_t)(kq + srow0) * DI + sch * 8);
    uint4 ka1 = *(const uint4*)(kp + (size_t)(kq + srow1) * DI + sch * 8);
    uint4 va0 = *(const uint4*)(vp + (size_t)srow0 * HW + kq + sch * 8);
    uint4 va1 = *(const uint4*)(vp + (size_t)srow1 * HW + kq + sch * 8);
    *(uint4*)&Kb0[koff0] = ka0;  *(uint4*)&Kb0[koff1] = ka1;
    *(uint4*)&Vb0[voff0] = va0;  *(uint4*)&Vb0[voff1] = va1;
    ka0 = *(const uint4*)(kp + (size_t)(kq + 64 + srow0) * DI + sch * 8);
    ka1 = *(const uint4*)(kp + (size_t)(kq + 64 + srow1) * DI + sch * 8);
    va0 = *(const uint4*)(vp + (size_t)srow0 * HW + kq + 64 + sch * 8);
    va1 = *(const uint4*)(vp + (size_t)srow1 * HW + kq + 64 + sch * 8);
    __syncthreads();

    auto body = [&](int t, const u16* Kc, const u16* Vc, u16* Kn, u16* Vn) {
        // --- ISSUE-EARLY staging (this round's change): write tile t+1
        //     (regs loaded one body ago -> vmcnt long satisfied), then issue
        //     the t+2 loads so they land under QK+exp+PV before the barrier.
        if (t + 1 < HTILE) {
            *(uint4*)&Kn[koff0] = ka0; *(uint4*)&Kn[koff1] = ka1;
            *(uint4*)&Vn[voff0] = va0; *(uint4*)&Vn[voff1] = va1;
        }
        if (t + 2 < HTILE) {
            int tb = kq + (t + 2) * 64;
            ka0 = *(const uint4*)(kp + (size_t)(tb + srow0) * DI + sch * 8);
            ka1 = *(const uint4*)(kp + (size_t)(tb + srow1) * DI + sch * 8);
            va0 = *(const uint4*)(vp + (size_t)srow0 * HW + tb + sch * 8);
            va1 = *(const uint4*)(vp + (size_t)srow1 * HW + tb + sch * 8);
        }

        // --- swapped QK^T with permuted A rows (both q-sets share K frags) ---
        f32x4 stA[4], stB[4];
        __builtin_amdgcn_s_setprio(1);
        #pragma unroll
        for (int m = 0; m < 4; ++m) {
            const int kr = krbase + 4 * (m & 1) + 32 * (m >> 1);
            f16x8 a0 = *(const f16x8*)&Kc[kr * 64 + ((hi ^ xl) * 8)];
            f16x8 a1 = *(const f16x8*)&Kc[kr * 64 + (((4 + hi) ^ xl) * 8)];
            f32x4 zA = {0.f, 0.f, 0.f, 0.f};
            zA = __builtin_amdgcn_mfma_f32_16x16x32_f16(a0, qfA0, zA, 0, 0, 0);
            zA = __builtin_amdgcn_mfma_f32_16x16x32_f16(a1, qfA1, zA, 0, 0, 0);
            stA[m] = zA;
            f32x4 zB = {0.f, 0.f, 0.f, 0.f};
            zB = __builtin_amdgcn_mfma_f32_16x16x32_f16(a0, qfB0, zB, 0, 0, 0);
            zB = __builtin_amdgcn_mfma_f32_16x16x32_f16(a1, qfB1, zB, 0, 0, 0);
            stB[m] = zB;
        }
        __builtin_amdgcn_s_setprio(0);

        // --- P = 2^(S') -> bf16 (q pre-scaled by log2e; bare v_exp_f32) ---
        bf16x8 paA0, paA1, paB0, paB1;
        #pragma unroll
        for (int m = 0; m < 4; ++m) {
            __bf16 b0 = (__bf16)exp2v(stA[m][0]);
            __bf16 b1 = (__bf16)exp2v(stA[m][1]);
            __bf16 b2 = (__bf16)exp2v(stA[m][2]);
            __bf16 b3 = (__bf16)exp2v(stA[m][3]);
            if (m == 0)      { paA0[0] = b0; paA0[1] = b1; paA0[2] = b2; paA0[3] = b3; }
            else if (m == 1) { paA0[4] = b0; paA0[5] = b1; paA0[6] = b2; paA0[7] = b3; }
            else if (m == 2) { paA1[0] = b0; paA1[1] = b1; paA1[2] = b2; paA1[3] = b3; }
            else             { paA1[4] = b0; paA1[5] = b1; paA1[6] = b2; paA1[7] = b3; }
        }
        #pragma unroll
        for (int m = 0; m < 4; ++m) {
            __bf16 b0 = (__bf16)exp2v(stB[m][0]);
            __bf16 b1 = (__bf16)exp2v(stB[m][1]);
            __bf16 b2 = (__bf16)exp2v(stB[m][2]);
            __bf16 b3 = (__bf16)exp2v(stB[m][3]);
            if (m == 0)      { paB0[0] = b0; paB0[1] = b1; paB0[2] = b2; paB0[3] = b3; }
            else if (m == 1) { paB0[4] = b0; paB0[5] = b1; paB0[6] = b2; paB0[7] = b3; }
            else if (m == 2) { paB1[0] = b0; paB1[1] = b1; paB1[2] = b2; paB1[3] = b3; }
            else             { paB1[4] = b0; paB1[5] = b1; paB1[6] = b2; paB1[7] = b3; }
        }

        // --- PV + l row-sums (l on the MFMA pipe, keys summed via ones) ---
        __builtin_amdgcn_s_setprio(1);
        laccA4 = __builtin_amdgcn_mfma_f32_16x16x32_bf16(paA0, vone, laccA4, 0, 0, 0);
        laccA4 = __builtin_amdgcn_mfma_f32_16x16x32_bf16(paA1, vone, laccA4, 0, 0, 0);
        laccB4 = __builtin_amdgcn_mfma_f32_16x16x32_bf16(paB0, vone, laccB4, 0, 0, 0);
        laccB4 = __builtin_amdgcn_mfma_f32_16x16x32_bf16(paB1, vone, laccB4, 0, 0, 0);
        #pragma unroll
        for (int nf = 0; nf < 4; ++nf) {
            const int vr = nf * 16 + lo;
            bf16x8 v0 = *(const bf16x8*)&Vc[vr * 64 + ((hi ^ xl) * 8)];
            bf16x8 v1 = *(const bf16x8*)&Vc[vr * 64 + (((4 + hi) ^ xl) * 8)];
            yaccA[nf] = __builtin_amdgcn_mfma_f32_16x16x32_bf16(paA0, v0, yaccA[nf], 0, 0, 0);
            yaccA[nf] = __builtin_amdgcn_mfma_f32_16x16x32_bf16(paA1, v1, yaccA[nf], 0, 0, 0);
            yaccB[nf] = __builtin_amdgcn_mfma_f32_16x16x32_bf16(paB0, v0, yaccB[nf], 0, 0, 0);
            yaccB[nf] = __builtin_amdgcn_mfma_f32_16x16x32_bf16(paB1, v1, yaccB[nf], 0, 0, 0);
        }
        __builtin_amdgcn_s_setprio(0);

        __syncthreads();                          // t+2 loads landed under body
    };

    #pragma unroll 1
    for (int tt = 0; tt < HTILE; tt += 2) {
        body(tt,     Kb0, Vb0, Kb1, Vb1);
        body(tt + 1, Kb1, Vb1, Kb0, Vb0);
    }

    // --- finalize: lane already holds l for its D-layout rows q=4hi+r ---
    float invqA[4], invqB[4];
    #pragma unroll
    for (int r = 0; r < 4; ++r) {
        invqA[r] = 1.f / laccA4[r];
        invqB[r] = 1.f / laccB4[r];
    }
    if (lo == 0) {                                // store l for combine weights
        size_t lb = ((size_t)j * NBATCH + n) * HW + P0 + w4 * 32;
        #pragma unroll
        for (int r = 0; r < 4; ++r) {
            lp[lb + 4 * hi + r]      = laccA4[r];
            lp[lb + 16 + 4 * hi + r] = laccB4[r];
        }
    }

    __syncthreads();                              // done with K/V buffers
    u16* yw = smem;                               // [128][72] fp16 restage
    #pragma unroll
    for (int nf = 0; nf < 4; ++nf)
        #pragma unroll
        for (int r = 0; r < 4; ++r) {
            yw[(w4 * 32 + 4 * hi + r) * 72 + nf * 16 + lo]      = f2h(yaccA[nf][r] * invqA[r]);
            yw[(w4 * 32 + 16 + 4 * hi + r) * 72 + nf * 16 + lo] = f2h(yaccB[nf][r] * invqB[r]);
        }
    __syncthreads();

    // --- write partials into combine-block regions of d_out ---
    u32* outb = (u32*)outF + (size_t)n * CCH * HW + (size_t)j * 32 * HW;
    const int ptb = P0 >> 6;
    #pragma unroll
    for (int s = 0; s < 4; ++s) {
        int idx = tid + s * 256;                  // 1024 x 16B chunks
        int T   = idx >> 3, d0 = (idx & 7) * 8;
        int tok = T & 63;
        int f   = (tok >> 1) * HW + (ptb + (T >> 6)) * 64 + (tok & 1) * 32 + (d0 >> 1);
        *(uint4*)&outb[f] = *(const uint4*)&yw[T * 72 + d0];
    }
}

// ---------------------------------------------------------------------------
// Kernel 3: combine 4 partials (2 pass x 2 key-half) + z-projection +
// residual via fp16 MFMA (validated R13).
// ---------------------------------------------------------------------------
__global__ __launch_bounds__(256) void combine_kernel(
    float* __restrict__ outF, const float* __restrict__ lp,
    const u16* __restrict__ Wzf, const float* __restrict__ bz,
    const float* __restrict__ F)
{
    __shared__ __align__(16) float zs[64 * 129];
    const int tid  = threadIdx.x;
    const int n    = blockIdx.x / NTILE;
    const int p0   = (blockIdx.x % NTILE) * 64;
    const int lane = tid & 63, wave = tid >> 6;
    const int lo   = lane & 15, hi = lane >> 4;
    const int tok  = wave * 16 + lo;              // local token (A-frag row)

    const u32* pb = (const u32*)outF + (size_t)n * CCH * HW;
    f16x8 af[4][2];
    #pragma unroll
    for (int jj = 0; jj < 4; ++jj)
        #pragma unroll
        for (int ks = 0; ks < 2; ++ks)
            af[jj][ks] = *(const f16x8*)&pb[(size_t)(jj * 32 + (tok >> 1)) * HW
                                            + p0 + (tok & 1) * 32 + ks * 16 + hi * 4];
    float lw[4];
    #pragma unroll
    for (int jj = 0; jj < 4; ++jj)
        lw[jj] = lp[((size_t)jj * NBATCH + n) * HW + p0 + tok];
    float s0 = 1.f / (lw[0] + lw[1]);
    float s1 = 1.f / (lw[2] + lw[3]);
    _Float16 w00 = (_Float16)(lw[0] * s0), w01 = (_Float16)(lw[1] * s0);
    _Float16 w10 = (_Float16)(lw[2] * s1), w11 = (_Float16)(lw[3] * s1);
    f16x8 a00 = af[0][0] * w00 + af[1][0] * w01;
    f16x8 a01 = af[0][1] * w00 + af[1][1] * w01;
    f16x8 a10 = af[2][0] * w10 + af[3][0] * w11;
    f16x8 a11 = af[2][1] * w10 + af[3][1] * w11;

    f32x4 acc[8];
    #pragma unroll
    for (int g = 0; g < 8; ++g)
        #pragma unroll
        for (int r = 0; r < 4; ++r) acc[g][r] = 0.f;

    #pragma unroll
    for (int g = 0; g < 8; ++g) {
        f16x8 b0 = *(const f16x8*)&Wzf[(size_t)((g * 2 + 0) * 64 + lane) * 8];
        f16x8 b1 = *(const f16x8*)&Wzf[(size_t)((g * 2 + 1) * 64 + lane) * 8];
        acc[g] = __builtin_amdgcn_mfma_f32_16x16x32_f16(a00, b0, acc[g], 0, 0, 0);
        acc[g] = __builtin_amdgcn_mfma_f32_16x16x32_f16(a01, b1, acc[g], 0, 0, 0);
        acc[g] = __builtin_amdgcn_mfma_f32_16x16x32_f16(a10, b0, acc[g], 0, 0, 0);
        acc[g] = __builtin_amdgcn_mfma_f32_16x16x32_f16(a11, b1, acc[g], 0, 0, 0);
    }

    #pragma unroll
    for (int g = 0; g < 8; ++g)
        #pragma unroll
        for (int r = 0; r < 4; ++r)
            zs[(wave * 16 + 4 * hi + r) * 129 + g * 16 + lo] = acc[g][r];
    __syncthreads();

    #pragma unroll 4
    for (int i = 0; i < 32; ++i) {
        int c = wave + 4 * i;
        size_t gi = (size_t)(n * CCH + c) * HW + p0 + lane;
        outF[gi] = zs[lane * 129 + c] + 2.f * bz[c] + F[gi];
    }
}

extern "C" void kernel_launch(void* const* d_in, const int* in_sizes, int n_in,
                              void* d_out, int out_size, void* d_ws, size_t ws_size,
                              hipStream_t stream) {
    const float* F  = (const float*)d_in[0];
    const float* Wq = (const float*)d_in[1];
    const float* bq = (const float*)d_in[2];
    const float* Wk = (const float*)d_in[3];
    const float* bk = (const float*)d_in[4];
    const float* Wv = (const float*)d_in[5];
    const float* bv = (const float*)d_in[6];
    const float* Wz = (const float*)d_in[7];
    const float* bz = (const float*)d_in[8];
    float* outp = (float*)d_out;

    const size_t tok = (size_t)NBATCH * HW * DI;   // 2,359,296 elements
    u16*   qb  = (u16*)d_ws;                       // fp16 (pre-scaled by log2e)
    u16*   kb  = qb  + tok;                        // fp16
    u16*   vtb = kb  + tok;                        // bf16, transposed
    u16*   wf  = vtb + tok;                        // 24576 fp16 frag-ordered Wq/Wk/Wv
    u16*   wzf = wf  + 24576;                      //  8192 fp16 frag-ordered Wz
    float* lpb = (float*)(wzf + 8192);             // 4*16*2304 fp32 l partials
    // total ws: 3*tok*2B + 65KB + 590KB ~= 14.8 MB (partials live in d_out)

    wprep_kernel<<<16, 256, 0, stream>>>(Wq, Wk, Wv, Wz, wf, wzf);
    proj_kernel<<<NBATCH * NTILE, 256, 0, stream>>>(F, wf, bq, bk, bv, qb, kb, vtb);
    attn_pass_kernel<<<4 * NBATCH * QBLK, 256, 0, stream>>>(qb, kb, vtb, outp, lpb);
    combine_kernel<<<NBATCH * NTILE, 256, 0, stream>>>(outp, lpb, wzf, bz, F);
}